// Round 6
// baseline (1076.723 us; speedup 1.0000x reference)
//
#include <hip/hip_runtime.h>
#include <hip/hip_bf16.h>
#include <cstddef>

// Problem constants
#define BB   8
#define CIN  16
#define COUT 16
#define TT   32
#define HH   16
#define WW   16
#define DIN  4096
#define DOUT 4096
#define NH   4
#define DH   1024
#define SPAT 8192            // T*H*W
#define NSEQ 256             // B*T

typedef __attribute__((ext_vector_type(8))) short  bf16x8;
typedef __attribute__((ext_vector_type(4))) float  f32x4;
typedef __attribute__((ext_vector_type(4))) unsigned short us4;
typedef unsigned short ushort_t;

static __device__ __forceinline__ ushort_t f2bf(float f) {
    union { float f; unsigned u; } v; v.f = f;
    unsigned r = (v.u + 0x7fffu + ((v.u >> 16) & 1u)) >> 16;
    return (ushort_t)r;
}
static __device__ __forceinline__ float bf2f(ushort_t u) {
    union { unsigned u; float f; } v; v.u = ((unsigned)u) << 16;
    return v.f;
}

// ---------------------------------------------------------------------------
// pack x (B,16,32,16,16) fp32 -> xt[n=b*32+t][k=c*256+hw] bf16
// ---------------------------------------------------------------------------
__global__ void pack_xt_kernel(const float* __restrict__ x, ushort_t* __restrict__ xt) {
    int idx = blockIdx.x * 256 + threadIdx.x;          // 0 .. 262143 (4 elems each)
    int n = idx >> 10, k4 = (idx & 1023) * 4;
    int b = n >> 5, t = n & 31, c = k4 >> 8, hw = k4 & 255;
    f32x4 f = *(const f32x4*)&x[(((size_t)(b * CIN + c) * TT + t)) * 256 + hw];
    us4 o;
    #pragma unroll
    for (int i = 0; i < 4; ++i) o[i] = f2bf(f[i]);
    *(us4*)&xt[(size_t)n * DIN + k4] = o;
}

// ---------------------------------------------------------------------------
// pack R (4,4,1024,1024) fp32 -> bf16 in MFMA-fragment order:
// Rp[((head*64+oc)*4+g)*32+ks][lane][e] = R[head][g][oc*16+(lane&15)][ks*32+(lane>>4)*8+e]
// ---------------------------------------------------------------------------
__global__ void pack_R_kernel(const float* __restrict__ R, ushort_t* __restrict__ Rp) {
    int vid = blockIdx.x * 256 + threadIdx.x;   // 0 .. 2097151
    int l  = vid & 63;
    int ks = (vid >> 6) & 31;
    int g  = (vid >> 11) & 3;
    int oc = (vid >> 13) & 63;
    int hd = vid >> 19;
    int arow = l & 15, kI = l >> 4;
    const float* src = R + ((size_t)((hd * 4 + g) * DH + oc * 16 + arow)) * DH
                         + ks * 32 + kI * 8;
    f32x4 f0 = *(const f32x4*)src;
    f32x4 f1 = *(const f32x4*)(src + 4);
    union { ushort_t u[8]; bf16x8 v; } pk;
    #pragma unroll
    for (int j = 0; j < 4; ++j) { pk.u[j] = f2bf(f0[j]); pk.u[4 + j] = f2bf(f1[j]); }
    ((bf16x8*)Rp)[vid] = pk.v;
}

// ---------------------------------------------------------------------------
// MFMA GEMM, single M-tile: C[256][N] = A[256][K](bf16) * B[N][K]^T(fp32) + bias
// BM=256 BN=64 BK=64, 256 threads (4 waves), double-buffered LDS.
// ---------------------------------------------------------------------------
template<bool OUT_BF16>
__global__ __launch_bounds__(256, 2)
void mfma_gemm_kernel(const ushort_t* __restrict__ A, const float* __restrict__ B,
                      const float* __restrict__ bias, void* __restrict__ C,
                      int N, int K) {
    __shared__ ushort_t Al[2][256][64];   // 64 KB
    __shared__ ushort_t Bl[2][64][64];    // 16 KB
    int tid  = threadIdx.x;
    int lane = tid & 63;
    int wv   = tid >> 6;       // 0..3 : wave owns rows [wv*64, wv*64+64)
    int n0 = blockIdx.x * 64;

    f32x4 acc[4][4];
    #pragma unroll
    for (int i = 0; i < 4; ++i)
        #pragma unroll
        for (int j = 0; j < 4; ++j) acc[i][j] = (f32x4){0.f, 0.f, 0.f, 0.f};

    auto stageA = [&](int buf, int k0) {
        #pragma unroll
        for (int q = 0; q < 8; ++q) {
            int row = wv * 64 + q * 8 + (lane >> 3);
            const ushort_t* g = A + (size_t)row * K + k0 + (lane & 7) * 8;
            __builtin_amdgcn_global_load_lds(
                (const __attribute__((address_space(1))) void*)g,
                (__attribute__((address_space(3))) void*)&Al[buf][wv * 64 + q * 8][0],
                16, 0, 0);
        }
    };
    auto stageB = [&](int buf, int k0) {
        int r = tid >> 2;               // 0..63
        int cs = (tid & 3) * 16;        // 0,16,32,48
        const float* g = B + (size_t)(n0 + r) * K + k0 + cs;
        f32x4 f0 = *(const f32x4*)(g);
        f32x4 f1 = *(const f32x4*)(g + 4);
        f32x4 f2 = *(const f32x4*)(g + 8);
        f32x4 f3 = *(const f32x4*)(g + 12);
        union { ushort_t u[16]; bf16x8 v[2]; } pk;
        #pragma unroll
        for (int i = 0; i < 4; ++i) {
            pk.u[i]      = f2bf(f0[i]);
            pk.u[4 + i]  = f2bf(f1[i]);
            pk.u[8 + i]  = f2bf(f2[i]);
            pk.u[12 + i] = f2bf(f3[i]);
        }
        *(bf16x8*)&Bl[buf][r][cs]     = pk.v[0];
        *(bf16x8*)&Bl[buf][r][cs + 8] = pk.v[1];
    };
    auto compute = [&](int buf) {
        #pragma unroll
        for (int ks = 0; ks < 2; ++ks) {
            bf16x8 af[4], bfr[4];
            #pragma unroll
            for (int i = 0; i < 4; ++i)
                af[i] = *(const bf16x8*)&Al[buf][wv * 64 + i * 16 + (lane & 15)][ks * 32 + (lane >> 4) * 8];
            #pragma unroll
            for (int j = 0; j < 4; ++j)
                bfr[j] = *(const bf16x8*)&Bl[buf][j * 16 + (lane & 15)][ks * 32 + (lane >> 4) * 8];
            #pragma unroll
            for (int i = 0; i < 4; ++i)
                #pragma unroll
                for (int j = 0; j < 4; ++j)
                    acc[i][j] = __builtin_amdgcn_mfma_f32_16x16x32_bf16(af[i], bfr[j], acc[i][j], 0, 0, 0);
        }
    };

    stageA(0, 0); stageB(0, 0);
    __syncthreads();
    int nk = K / 64;
    int cur = 0;
    for (int t = 0; t < nk; ++t) {
        if (t + 1 < nk) { stageA(cur ^ 1, (t + 1) * 64); stageB(cur ^ 1, (t + 1) * 64); }
        compute(cur);
        __syncthreads();
        cur ^= 1;
    }

    #pragma unroll
    for (int i = 0; i < 4; ++i) {
        int row = wv * 64 + i * 16 + (lane >> 4) * 4;
        #pragma unroll
        for (int j = 0; j < 4; ++j) {
            int col = n0 + j * 16 + (lane & 15);
            float bv = bias[col];
            #pragma unroll
            for (int r = 0; r < 4; ++r) {
                float v = acc[i][j][r] + bv;
                if constexpr (OUT_BF16) ((ushort_t*)C)[(size_t)(row + r) * N + col] = f2bf(v);
                else                    ((float*)C)[(size_t)(row + r) * N + col] = v;
            }
        }
    }
}

// ---------------------------------------------------------------------------
// Persistent sLSTM: R staged once into LDS; 32 steps with per-head flag sync.
// grid: 256 blocks = head(4) x ochunk(64 of 16 o's), 256 threads, 1 block/CU.
// wave = K-chunk (8 ks each), all 4 gates per wave; partial-gh reduce in LDS.
// h exchanged via global ping-pong (hi+lo bf16, packed into MFMA cols 0-7/8-15,
// folded with shfl_xor(8)).  c/n/m state lives in registers.
// ---------------------------------------------------------------------------
__global__ __launch_bounds__(256, 1)
void lstm_persist_kernel(const ushort_t* __restrict__ Rp,   // packed bf16 (32 MB)
                         const float* __restrict__ Gx,      // [256][16384]
                         ushort_t* __restrict__ hA_hi, ushort_t* __restrict__ hA_lo,
                         ushort_t* __restrict__ hB_hi, ushort_t* __restrict__ hB_lo,
                         float* __restrict__ hs,
                         int* __restrict__ flags) {         // [32][4], zeroed
    __shared__ ushort_t Rl[4][32][64 * 8];   // [gate][ks][lane*8] = 128 KB
    __shared__ float gh_p[4][4][16][8];      // [wave][gate][o_l][b] = 8 KB

    int tid  = threadIdx.x;
    int lane = tid & 63;
    int w    = tid >> 6;               // wave = K-chunk (ks in [w*8, w*8+8))
    int head = blockIdx.x >> 6;
    int oc   = blockIdx.x & 63;

    // ---- stage packed R slice (contiguous 128 KB) into LDS, once ----
    const bf16x8* Rsrc = (const bf16x8*)Rp + (size_t)((head * 64 + oc) * 4) * 32 * 64;
    bf16x8* Rdst = (bf16x8*)&Rl[0][0][0];
    for (int i = tid; i < 4 * 32 * 64; i += 256) Rdst[i] = Rsrc[i];

    int arow = lane & 15;          // packed-B column (part,bb); also D column
    int part = arow >> 3;          // 0: hi half of h, 1: lo half
    int bb   = arow & 7;           // batch
    int kseg = lane >> 4;          // 0..3

    // gate-phase identity (tid < 128)
    int gb  = tid >> 4;            // batch
    int gol = tid & 15;            // o_local
    int gd  = head * DH + oc * 16 + gol;
    float c_r = 0.f, n_r = 0.f, m_r = 0.f;

    __syncthreads();

    for (int t = 0; t < TT; ++t) {
        if (t > 0) {
            if (tid == 0) {
                while (__hip_atomic_load(&flags[(t - 1) * 4 + head],
                        __ATOMIC_RELAXED, __HIP_MEMORY_SCOPE_AGENT) < 64) {}
            }
            __syncthreads();
            __builtin_amdgcn_fence(__ATOMIC_ACQUIRE, "agent");

            const ushort_t* base_hi = (t & 1) ? hA_hi : hB_hi;   // written at t-1
            const ushort_t* base_lo = (t & 1) ? hA_lo : hB_lo;
            const ushort_t* Hp = (part ? base_lo : base_hi)
                                 + (size_t)bb * DOUT + head * DH + kseg * 8;
            bf16x8 hf[8];
            #pragma unroll
            for (int j = 0; j < 8; ++j)
                hf[j] = *(const bf16x8*)(Hp + (w * 8 + j) * 32);

            f32x4 acc[4];
            #pragma unroll
            for (int g = 0; g < 4; ++g) acc[g] = (f32x4){0.f, 0.f, 0.f, 0.f};
            #pragma unroll
            for (int g = 0; g < 4; ++g)
                #pragma unroll
                for (int j = 0; j < 8; ++j) {
                    bf16x8 a = *(const bf16x8*)&Rl[g][w * 8 + j][lane * 8];
                    acc[g] = __builtin_amdgcn_mfma_f32_16x16x32_bf16(a, hf[j], acc[g], 0, 0, 0);
                }
            // fold hi+lo halves (partner column = col^8 -> lane^8)
            #pragma unroll
            for (int g = 0; g < 4; ++g)
                #pragma unroll
                for (int r = 0; r < 4; ++r)
                    acc[g][r] += __shfl_xor(acc[g][r], 8, 64);
            // D layout: col = lane&15, row = kseg*4 + r
            if (part == 0) {
                int orow0 = kseg * 4;
                #pragma unroll
                for (int g = 0; g < 4; ++g)
                    #pragma unroll
                    for (int r = 0; r < 4; ++r)
                        gh_p[w][g][orow0 + r][bb] = acc[g][r];
            }
        } else {
            for (int i = tid; i < 4 * 4 * 16 * 8; i += 256)
                ((float*)gh_p)[i] = 0.f;
        }
        __syncthreads();

        if (tid < 128) {
            size_t gxoff = ((size_t)(gb * TT + t)) * (4 * DOUT) + gd;
            float ip = Gx[gxoff] +
                gh_p[0][0][gol][gb] + gh_p[1][0][gol][gb] + gh_p[2][0][gol][gb] + gh_p[3][0][gol][gb];
            float fp = Gx[gxoff + DOUT] +
                gh_p[0][1][gol][gb] + gh_p[1][1][gol][gb] + gh_p[2][1][gol][gb] + gh_p[3][1][gol][gb];
            float zp = Gx[gxoff + 2 * DOUT] +
                gh_p[0][2][gol][gb] + gh_p[1][2][gol][gb] + gh_p[2][2][gol][gb] + gh_p[3][2][gol][gb];
            float op = Gx[gxoff + 3 * DOUT] +
                gh_p[0][3][gol][gb] + gh_p[1][3][gol][gb] + gh_p[2][3][gol][gb] + gh_p[3][3][gol][gb];
            float mn = fmaxf(fp + m_r, ip);
            float iv = expf(ip - mn);
            float fv = expf(fp + m_r - mn);
            c_r = fv * c_r + iv * tanhf(zp);
            n_r = fv * n_r + iv;
            float sig = 1.f / (1.f + expf(-op));
            float hv = sig * c_r / n_r;
            m_r = mn;
            hs[((size_t)(gb * TT + t)) * DOUT + gd] = hv;
            ushort_t hi = f2bf(hv);
            ushort_t* whi = (t & 1) ? hB_hi : hA_hi;
            ushort_t* wlo = (t & 1) ? hB_lo : hA_lo;
            whi[(size_t)gb * DOUT + gd] = hi;
            wlo[(size_t)gb * DOUT + gd] = f2bf(hv - bf2f(hi));
        }
        __syncthreads();   // drains this block's stores (vmcnt) before signal
        if (tid == 0)
            __hip_atomic_fetch_add(&flags[t * 4 + head], 1,
                                   __ATOMIC_RELEASE, __HIP_MEMORY_SCOPE_AGENT);
    }
}

// ---------------------------------------------------------------------------
// conv3d 3x3x3 pad=1: one block per (b,t); LDS-staged input slice + weights.
// ---------------------------------------------------------------------------
__global__ __launch_bounds__(256)
void conv3d_kernel(const float* __restrict__ in, const float* __restrict__ w,
                   const float* __restrict__ bias, float* __restrict__ out, int relu) {
    __shared__ float xin[CIN][3][256];      // 48 KB
    __shared__ float wl[CIN][27][16];       // 27 KB, o-fastest
    int b = blockIdx.x >> 5, t = blockIdx.x & 31;
    int tid = threadIdx.x;

    for (int i = tid; i < CIN * 27 * 16; i += 256) {
        int o = i & 15, r = i >> 4;
        int k = r % 27, ci = r / 27;
        wl[ci][k][o] = w[(size_t)(o * CIN + ci) * 27 + k];
    }
    for (int i = tid; i < CIN * 3 * 256; i += 256) {
        int hw = i & 255, r = i >> 8;
        int kt = r % 3, ci = r / 3;
        int tt = t + kt - 1;
        xin[ci][kt][hw] = ((unsigned)tt < TT)
            ? in[((size_t)(b * CIN + ci) * TT + tt) * 256 + hw] : 0.f;
    }
    __syncthreads();

    int h = tid >> 4, wx = tid & 15;
    f32x4 a0 = *(const f32x4*)&bias[0];
    f32x4 a1 = *(const f32x4*)&bias[4];
    f32x4 a2 = *(const f32x4*)&bias[8];
    f32x4 a3 = *(const f32x4*)&bias[12];

    for (int ci = 0; ci < CIN; ++ci) {
        #pragma unroll
        for (int kt = 0; kt < 3; ++kt) {
            #pragma unroll
            for (int kh = 0; kh < 3; ++kh) {
                int h2 = h + kh - 1;
                if ((unsigned)h2 >= HH) continue;
                #pragma unroll
                for (int kw = 0; kw < 3; ++kw) {
                    int w2 = wx + kw - 1;
                    if ((unsigned)w2 >= WW) continue;
                    float xv = xin[ci][kt][h2 * 16 + w2];
                    int k = kt * 9 + kh * 3 + kw;
                    f32x4 w0 = *(const f32x4*)&wl[ci][k][0];
                    f32x4 w1 = *(const f32x4*)&wl[ci][k][4];
                    f32x4 w2v = *(const f32x4*)&wl[ci][k][8];
                    f32x4 w3 = *(const f32x4*)&wl[ci][k][12];
                    a0 += xv * w0; a1 += xv * w1; a2 += xv * w2v; a3 += xv * w3;
                }
            }
        }
    }
    float accs[16];
    #pragma unroll
    for (int i = 0; i < 4; ++i) { accs[i] = a0[i]; accs[4+i] = a1[i]; accs[8+i] = a2[i]; accs[12+i] = a3[i]; }
    #pragma unroll
    for (int o = 0; o < 16; ++o) {
        float v = accs[o];
        if (relu) v = fmaxf(v, 0.f);
        out[((size_t)(b * COUT + o) * TT + t) * 256 + tid] = v;
    }
}

// ---------------------------------------------------------------------------
// instance norm over (T,H,W) per (b,c) + relu, in place. 128 blocks.
// ---------------------------------------------------------------------------
__global__ void inorm_relu_kernel(float* __restrict__ y) {
    __shared__ float s1[256], s2[256];
    float* p = y + (size_t)blockIdx.x * SPAT;
    float sum = 0.f, sq = 0.f;
    for (int i = threadIdx.x; i < SPAT; i += 256) {
        float v = p[i];
        sum += v; sq += v * v;
    }
    s1[threadIdx.x] = sum; s2[threadIdx.x] = sq;
    __syncthreads();
    for (int s = 128; s > 0; s >>= 1) {
        if (threadIdx.x < s) { s1[threadIdx.x] += s1[threadIdx.x + s]; s2[threadIdx.x] += s2[threadIdx.x + s]; }
        __syncthreads();
    }
    float mu = s1[0] / (float)SPAT;
    float var = s2[0] / (float)SPAT - mu * mu;
    float rs = rsqrtf(var + 1e-5f);
    for (int i = threadIdx.x; i < SPAT; i += 256) {
        float v = (p[i] - mu) * rs;
        p[i] = fmaxf(v, 0.f);
    }
}

// ---------------------------------------------------------------------------
// final combine
// ---------------------------------------------------------------------------
__global__ void combine_kernel(const float* __restrict__ hs,
                               const float* __restrict__ out3d,
                               const float* __restrict__ attn_w,
                               const float* __restrict__ attn_b,
                               float* __restrict__ out) {
    int idx = blockIdx.x * 256 + threadIdx.x;
    int hw = idx & 255;
    int t  = (idx >> 8) & 31;
    int b  = idx >> 13;
    const float* hrow = hs + ((size_t)(b * TT + t)) * DOUT;
    float dot = attn_b[0];
    float sv[16], ov[16];
    #pragma unroll
    for (int ch = 0; ch < 16; ++ch) {
        float s  = hrow[ch * 256 + hw];
        float o3 = out3d[(((size_t)(b * COUT + ch) * TT + t)) * 256 + hw];
        sv[ch] = s; ov[ch] = o3;
        dot += attn_w[ch] * s + attn_w[16 + ch] * o3;
    }
    float alpha = 1.f / (1.f + expf(-dot));
    #pragma unroll
    for (int ch = 0; ch < 16; ++ch) {
        out[(((size_t)(b * COUT + ch) * TT + t)) * 256 + hw] =
            alpha * ov[ch] + (1.f - alpha) * sv[ch];
    }
}

// ---------------------------------------------------------------------------
extern "C" void kernel_launch(void* const* d_in, const int* in_sizes, int n_in,
                              void* d_out, int out_size, void* d_ws, size_t ws_size,
                              hipStream_t stream) {
    const float* x      = (const float*)d_in[0];
    const float* c1_w   = (const float*)d_in[1];
    const float* c1_b   = (const float*)d_in[2];
    const float* c2_w   = (const float*)d_in[3];
    const float* c2_b   = (const float*)d_in[4];
    const float* c3_w   = (const float*)d_in[5];
    const float* c3_b   = (const float*)d_in[6];
    const float* pre_w  = (const float*)d_in[7];
    const float* pre_b  = (const float*)d_in[8];
    const float* lstm_W = (const float*)d_in[9];
    const float* lstm_b = (const float*)d_in[10];
    const float* lstm_R = (const float*)d_in[11];
    const float* attn_w = (const float*)d_in[12];
    const float* attn_b = (const float*)d_in[13];
    float* out = (float*)d_out;

    // workspace carve (fp32 first, then bf16; all 16B aligned)
    float* wsf = (float*)d_ws;
    float* y1    = wsf;                // 1048576
    float* y2    = y1 + 1048576;       // 1048576
    float* out3d = y2 + 1048576;       // 1048576
    float* hs    = out3d + 1048576;    // 1048576
    float* Gx    = hs + 1048576;       // 4194304
    ushort_t* xt    = (ushort_t*)(Gx + 4194304);  // 1048576
    ushort_t* xs2b  = xt + 1048576;               // 1048576
    ushort_t* Rp    = xs2b + 1048576;             // 16777216 (packed R, 32 MB)
    ushort_t* hA_hi = Rp + 16777216;              // 32768 (8 x 4096)
    ushort_t* hA_lo = hA_hi + 32768;              // 32768
    ushort_t* hB_hi = hA_lo + 32768;              // 32768
    ushort_t* hB_lo = hB_hi + 32768;              // 32768
    int*      flags = (int*)(hB_lo + 32768);      // 128 ints

    // zero sync flags (h buffers not read at t=0; c/n/m live in registers)
    hipMemsetAsync(flags, 0, 128 * sizeof(int), stream);

    // pack x -> bf16 sequence layout; pack R -> bf16 MFMA-fragment order
    pack_xt_kernel<<<1024, 256, 0, stream>>>(x, xt);
    pack_R_kernel<<<8192, 256, 0, stream>>>(lstm_R, Rp);

    // convs
    conv3d_kernel<<<256, 256, 0, stream>>>(x, c1_w, c1_b, y1, 0);
    inorm_relu_kernel<<<128, 256, 0, stream>>>(y1);
    conv3d_kernel<<<256, 256, 0, stream>>>(y1, c2_w, c2_b, y2, 1);
    conv3d_kernel<<<256, 256, 0, stream>>>(y2, c3_w, c3_b, out3d, 1);

    // pre-projection -> xs2 (bf16); gate projection -> Gx (fp32)
    mfma_gemm_kernel<true><<<DOUT / 64, 256, 0, stream>>>(xt, pre_w, pre_b, xs2b, DOUT, DIN);
    mfma_gemm_kernel<false><<<4 * DOUT / 64, 256, 0, stream>>>(xs2b, lstm_W, lstm_b, Gx, 4 * DOUT, DOUT);

    // recurrence: one persistent kernel, per-head flag sync (no cg barrier)
    lstm_persist_kernel<<<256, 256, 0, stream>>>(Rp, Gx, hA_hi, hA_lo, hB_hi, hB_lo,
                                                 hs, flags);

    // combine
    combine_kernel<<<256, 256, 0, stream>>>(hs, out3d, attn_w, attn_b, out);
}

// Round 7
// 797.927 us; speedup vs baseline: 1.3494x; 1.3494x over previous
//
#include <hip/hip_runtime.h>
#include <hip/hip_bf16.h>
#include <cstddef>

// Problem constants
#define BB   8
#define CIN  16
#define COUT 16
#define TT   32
#define HH   16
#define WW   16
#define DIN  4096
#define DOUT 4096
#define NH   4
#define DH   1024
#define SPAT 8192            // T*H*W
#define NSEQ 256             // B*T

typedef __attribute__((ext_vector_type(8))) short  bf16x8;
typedef __attribute__((ext_vector_type(4))) float  f32x4;
typedef __attribute__((ext_vector_type(4))) unsigned short us4;
typedef unsigned short ushort_t;

static __device__ __forceinline__ ushort_t f2bf(float f) {
    union { float f; unsigned u; } v; v.f = f;
    unsigned r = (v.u + 0x7fffu + ((v.u >> 16) & 1u)) >> 16;
    return (ushort_t)r;
}
static __device__ __forceinline__ float bf2f(ushort_t u) {
    union { unsigned u; float f; } v; v.u = ((unsigned)u) << 16;
    return v.f;
}

// ---------------------------------------------------------------------------
// pack x (B,16,32,16,16) fp32 -> xt[n=b*32+t][k=c*256+hw] bf16
// ---------------------------------------------------------------------------
__global__ void pack_xt_kernel(const float* __restrict__ x, ushort_t* __restrict__ xt) {
    int idx = blockIdx.x * 256 + threadIdx.x;          // 0 .. 262143 (4 elems each)
    int n = idx >> 10, k4 = (idx & 1023) * 4;
    int b = n >> 5, t = n & 31, c = k4 >> 8, hw = k4 & 255;
    f32x4 f = *(const f32x4*)&x[(((size_t)(b * CIN + c) * TT + t)) * 256 + hw];
    us4 o;
    #pragma unroll
    for (int i = 0; i < 4; ++i) o[i] = f2bf(f[i]);
    *(us4*)&xt[(size_t)n * DIN + k4] = o;
}

// ---------------------------------------------------------------------------
// pack R (4,4,1024,1024) fp32 -> bf16 in MFMA-fragment order:
// Rp[((head*64+oc)*4+g)*32+ks][lane][e] = R[head][g][oc*16+(lane&15)][ks*32+(lane>>4)*8+e]
// ---------------------------------------------------------------------------
__global__ void pack_R_kernel(const float* __restrict__ R, ushort_t* __restrict__ Rp) {
    int vid = blockIdx.x * 256 + threadIdx.x;   // 0 .. 2097151
    int l  = vid & 63;
    int ks = (vid >> 6) & 31;
    int g  = (vid >> 11) & 3;
    int oc = (vid >> 13) & 63;
    int hd = vid >> 19;
    int arow = l & 15, kI = l >> 4;
    const float* src = R + ((size_t)((hd * 4 + g) * DH + oc * 16 + arow)) * DH
                         + ks * 32 + kI * 8;
    f32x4 f0 = *(const f32x4*)src;
    f32x4 f1 = *(const f32x4*)(src + 4);
    union { ushort_t u[8]; bf16x8 v; } pk;
    #pragma unroll
    for (int j = 0; j < 4; ++j) { pk.u[j] = f2bf(f0[j]); pk.u[4 + j] = f2bf(f1[j]); }
    ((bf16x8*)Rp)[vid] = pk.v;
}

// ---------------------------------------------------------------------------
// MFMA GEMM, single M-tile: C[256][N] = A[256][K](bf16) * B[N][K]^T(fp32) + bias
// BM=256 BN=64 BK=64, 256 threads (4 waves), double-buffered LDS.
// ---------------------------------------------------------------------------
template<bool OUT_BF16>
__global__ __launch_bounds__(256, 2)
void mfma_gemm_kernel(const ushort_t* __restrict__ A, const float* __restrict__ B,
                      const float* __restrict__ bias, void* __restrict__ C,
                      int N, int K) {
    __shared__ ushort_t Al[2][256][64];   // 64 KB
    __shared__ ushort_t Bl[2][64][64];    // 16 KB
    int tid  = threadIdx.x;
    int lane = tid & 63;
    int wv   = tid >> 6;       // 0..3 : wave owns rows [wv*64, wv*64+64)
    int n0 = blockIdx.x * 64;

    f32x4 acc[4][4];
    #pragma unroll
    for (int i = 0; i < 4; ++i)
        #pragma unroll
        for (int j = 0; j < 4; ++j) acc[i][j] = (f32x4){0.f, 0.f, 0.f, 0.f};

    auto stageA = [&](int buf, int k0) {
        #pragma unroll
        for (int q = 0; q < 8; ++q) {
            int row = wv * 64 + q * 8 + (lane >> 3);
            const ushort_t* g = A + (size_t)row * K + k0 + (lane & 7) * 8;
            __builtin_amdgcn_global_load_lds(
                (const __attribute__((address_space(1))) void*)g,
                (__attribute__((address_space(3))) void*)&Al[buf][wv * 64 + q * 8][0],
                16, 0, 0);
        }
    };
    auto stageB = [&](int buf, int k0) {
        int r = tid >> 2;               // 0..63
        int cs = (tid & 3) * 16;        // 0,16,32,48
        const float* g = B + (size_t)(n0 + r) * K + k0 + cs;
        f32x4 f0 = *(const f32x4*)(g);
        f32x4 f1 = *(const f32x4*)(g + 4);
        f32x4 f2 = *(const f32x4*)(g + 8);
        f32x4 f3 = *(const f32x4*)(g + 12);
        union { ushort_t u[16]; bf16x8 v[2]; } pk;
        #pragma unroll
        for (int i = 0; i < 4; ++i) {
            pk.u[i]      = f2bf(f0[i]);
            pk.u[4 + i]  = f2bf(f1[i]);
            pk.u[8 + i]  = f2bf(f2[i]);
            pk.u[12 + i] = f2bf(f3[i]);
        }
        *(bf16x8*)&Bl[buf][r][cs]     = pk.v[0];
        *(bf16x8*)&Bl[buf][r][cs + 8] = pk.v[1];
    };
    auto compute = [&](int buf) {
        #pragma unroll
        for (int ks = 0; ks < 2; ++ks) {
            bf16x8 af[4], bfr[4];
            #pragma unroll
            for (int i = 0; i < 4; ++i)
                af[i] = *(const bf16x8*)&Al[buf][wv * 64 + i * 16 + (lane & 15)][ks * 32 + (lane >> 4) * 8];
            #pragma unroll
            for (int j = 0; j < 4; ++j)
                bfr[j] = *(const bf16x8*)&Bl[buf][j * 16 + (lane & 15)][ks * 32 + (lane >> 4) * 8];
            #pragma unroll
            for (int i = 0; i < 4; ++i)
                #pragma unroll
                for (int j = 0; j < 4; ++j)
                    acc[i][j] = __builtin_amdgcn_mfma_f32_16x16x32_bf16(af[i], bfr[j], acc[i][j], 0, 0, 0);
        }
    };

    stageA(0, 0); stageB(0, 0);
    __syncthreads();
    int nk = K / 64;
    int cur = 0;
    for (int t = 0; t < nk; ++t) {
        if (t + 1 < nk) { stageA(cur ^ 1, (t + 1) * 64); stageB(cur ^ 1, (t + 1) * 64); }
        compute(cur);
        __syncthreads();
        cur ^= 1;
    }

    #pragma unroll
    for (int i = 0; i < 4; ++i) {
        int row = wv * 64 + i * 16 + (lane >> 4) * 4;
        #pragma unroll
        for (int j = 0; j < 4; ++j) {
            int col = n0 + j * 16 + (lane & 15);
            float bv = bias[col];
            #pragma unroll
            for (int r = 0; r < 4; ++r) {
                float v = acc[i][j][r] + bv;
                if constexpr (OUT_BF16) ((ushort_t*)C)[(size_t)(row + r) * N + col] = f2bf(v);
                else                    ((float*)C)[(size_t)(row + r) * N + col] = v;
            }
        }
    }
}

// ---------------------------------------------------------------------------
// Persistent sLSTM, fence-free sync:
//  - h transported via hsp[t][b][d] (u32 = lo<<16 | hi bf16 pair), written/read
//    with RELAXED agent-scope atomics (cache-bypassing, Infinity-Cache coherent).
//    Per-t slots -> no WAR race, no ping-pong.
//  - per-(t,head) flag counter, RELAXED agent atomics; producer order by the
//    vmcnt drain in __syncthreads(); consumer order by barrier after poll.
//  - NO acquire/release fences (no buffer_inv / wbl2).
// grid: 256 blocks = head(4) x ochunk(64 of 16 o's), 256 threads, 1 block/CU.
// wave = K-chunk (8 ks each), all 4 gates per wave; partial-gh reduce in LDS.
// ---------------------------------------------------------------------------
__global__ __launch_bounds__(256, 1)
void lstm_persist_kernel(const ushort_t* __restrict__ Rp,   // packed bf16 (32 MB)
                         const float* __restrict__ Gx,      // [256][16384]
                         unsigned* __restrict__ hsp,        // [32][8][4096] u32
                         float* __restrict__ hs,            // [8][32][4096] f32
                         int* __restrict__ flags) {         // [32][4], zeroed
    __shared__ ushort_t Rl[4][32][64 * 8];   // [gate][ks][lane*8] = 128 KB
    __shared__ float gh_p[4][4][16][8];      // [wave][gate][o_l][b] = 8 KB

    int tid  = threadIdx.x;
    int lane = tid & 63;
    int w    = tid >> 6;               // wave = K-chunk (ks in [w*8, w*8+8))
    int head = blockIdx.x >> 6;
    int oc   = blockIdx.x & 63;

    // ---- stage packed R slice (contiguous 128 KB) into LDS, once ----
    const bf16x8* Rsrc = (const bf16x8*)Rp + (size_t)((head * 64 + oc) * 4) * 32 * 64;
    bf16x8* Rdst = (bf16x8*)&Rl[0][0][0];
    for (int i = tid; i < 4 * 32 * 64; i += 256) Rdst[i] = Rsrc[i];

    int arow = lane & 15;          // packed-B column (part,bb); also D column
    int part = arow >> 3;          // 0: hi half of h, 1: lo half
    int bb   = arow & 7;           // batch
    int kseg = lane >> 4;          // 0..3

    // gate-phase identity (tid < 128)
    int gb  = tid >> 4;            // batch
    int gol = tid & 15;            // o_local
    int gd  = head * DH + oc * 16 + gol;
    float c_r = 0.f, n_r = 0.f, m_r = 0.f;

    __syncthreads();

    for (int t = 0; t < TT; ++t) {
        // prefetch this step's Gx (h-independent) before the flag wait
        float gx0 = 0.f, gx1 = 0.f, gx2 = 0.f, gx3 = 0.f;
        if (tid < 128) {
            size_t gxoff = ((size_t)(gb * TT + t)) * (4 * DOUT) + gd;
            gx0 = Gx[gxoff];
            gx1 = Gx[gxoff + DOUT];
            gx2 = Gx[gxoff + 2 * DOUT];
            gx3 = Gx[gxoff + 3 * DOUT];
        }

        if (t > 0) {
            if (tid == 0) {
                while (__hip_atomic_load(&flags[(t - 1) * 4 + head],
                        __ATOMIC_RELAXED, __HIP_MEMORY_SCOPE_AGENT) < 64)
                    __builtin_amdgcn_s_sleep(1);
            }
            __syncthreads();   // orders h loads after flag observation

            const unsigned* hb = hsp + ((size_t)(t - 1) * 8 + bb) * DOUT
                                     + head * DH + kseg * 8;
            bf16x8 hf[8];
            #pragma unroll
            for (int j = 0; j < 8; ++j) {
                const unsigned* p = hb + (w * 8 + j) * 32;
                union { ushort_t u[8]; bf16x8 v; } fr;
                #pragma unroll
                for (int e = 0; e < 8; ++e) {
                    unsigned q = __hip_atomic_load(p + e, __ATOMIC_RELAXED,
                                                   __HIP_MEMORY_SCOPE_AGENT);
                    fr.u[e] = part ? (ushort_t)(q >> 16) : (ushort_t)(q & 0xffffu);
                }
                hf[j] = fr.v;
            }

            f32x4 acc[4];
            #pragma unroll
            for (int g = 0; g < 4; ++g) acc[g] = (f32x4){0.f, 0.f, 0.f, 0.f};
            #pragma unroll
            for (int g = 0; g < 4; ++g)
                #pragma unroll
                for (int j = 0; j < 8; ++j) {
                    bf16x8 a = *(const bf16x8*)&Rl[g][w * 8 + j][lane * 8];
                    acc[g] = __builtin_amdgcn_mfma_f32_16x16x32_bf16(a, hf[j], acc[g], 0, 0, 0);
                }
            // fold hi+lo halves (partner column = col^8 -> lane^8)
            #pragma unroll
            for (int g = 0; g < 4; ++g)
                #pragma unroll
                for (int r = 0; r < 4; ++r)
                    acc[g][r] += __shfl_xor(acc[g][r], 8, 64);
            // D layout: col = lane&15, row = kseg*4 + r
            if (part == 0) {
                int orow0 = kseg * 4;
                #pragma unroll
                for (int g = 0; g < 4; ++g)
                    #pragma unroll
                    for (int r = 0; r < 4; ++r)
                        gh_p[w][g][orow0 + r][bb] = acc[g][r];
            }
        } else {
            for (int i = tid; i < 4 * 4 * 16 * 8; i += 256)
                ((float*)gh_p)[i] = 0.f;
        }
        __syncthreads();

        if (tid < 128) {
            float ip = gx0 +
                gh_p[0][0][gol][gb] + gh_p[1][0][gol][gb] + gh_p[2][0][gol][gb] + gh_p[3][0][gol][gb];
            float fp = gx1 +
                gh_p[0][1][gol][gb] + gh_p[1][1][gol][gb] + gh_p[2][1][gol][gb] + gh_p[3][1][gol][gb];
            float zp = gx2 +
                gh_p[0][2][gol][gb] + gh_p[1][2][gol][gb] + gh_p[2][2][gol][gb] + gh_p[3][2][gol][gb];
            float op = gx3 +
                gh_p[0][3][gol][gb] + gh_p[1][3][gol][gb] + gh_p[2][3][gol][gb] + gh_p[3][3][gol][gb];
            float mn = fmaxf(fp + m_r, ip);
            float iv = expf(ip - mn);
            float fv = expf(fp + m_r - mn);
            c_r = fv * c_r + iv * tanhf(zp);
            n_r = fv * n_r + iv;
            float sig = 1.f / (1.f + expf(-op));
            float hv = sig * c_r / n_r;
            m_r = mn;
            hs[((size_t)(gb * TT + t)) * DOUT + gd] = hv;
            unsigned hi = f2bf(hv);
            unsigned lo = f2bf(hv - bf2f((ushort_t)hi));
            __hip_atomic_store(&hsp[((size_t)t * 8 + gb) * DOUT + gd],
                               hi | (lo << 16),
                               __ATOMIC_RELAXED, __HIP_MEMORY_SCOPE_AGENT);
        }
        __syncthreads();   // drains this block's stores (vmcnt) before signal
        if (tid == 0)
            __hip_atomic_fetch_add(&flags[t * 4 + head], 1,
                                   __ATOMIC_RELAXED, __HIP_MEMORY_SCOPE_AGENT);
    }
}

// ---------------------------------------------------------------------------
// conv3d 3x3x3 pad=1: one block per (b,t); LDS-staged input slice + weights.
// ---------------------------------------------------------------------------
__global__ __launch_bounds__(256)
void conv3d_kernel(const float* __restrict__ in, const float* __restrict__ w,
                   const float* __restrict__ bias, float* __restrict__ out, int relu) {
    __shared__ float xin[CIN][3][256];      // 48 KB
    __shared__ float wl[CIN][27][16];       // 27 KB, o-fastest
    int b = blockIdx.x >> 5, t = blockIdx.x & 31;
    int tid = threadIdx.x;

    for (int i = tid; i < CIN * 27 * 16; i += 256) {
        int o = i & 15, r = i >> 4;
        int k = r % 27, ci = r / 27;
        wl[ci][k][o] = w[(size_t)(o * CIN + ci) * 27 + k];
    }
    for (int i = tid; i < CIN * 3 * 256; i += 256) {
        int hw = i & 255, r = i >> 8;
        int kt = r % 3, ci = r / 3;
        int tt = t + kt - 1;
        xin[ci][kt][hw] = ((unsigned)tt < TT)
            ? in[((size_t)(b * CIN + ci) * TT + tt) * 256 + hw] : 0.f;
    }
    __syncthreads();

    int h = tid >> 4, wx = tid & 15;
    f32x4 a0 = *(const f32x4*)&bias[0];
    f32x4 a1 = *(const f32x4*)&bias[4];
    f32x4 a2 = *(const f32x4*)&bias[8];
    f32x4 a3 = *(const f32x4*)&bias[12];

    for (int ci = 0; ci < CIN; ++ci) {
        #pragma unroll
        for (int kt = 0; kt < 3; ++kt) {
            #pragma unroll
            for (int kh = 0; kh < 3; ++kh) {
                int h2 = h + kh - 1;
                if ((unsigned)h2 >= HH) continue;
                #pragma unroll
                for (int kw = 0; kw < 3; ++kw) {
                    int w2 = wx + kw - 1;
                    if ((unsigned)w2 >= WW) continue;
                    float xv = xin[ci][kt][h2 * 16 + w2];
                    int k = kt * 9 + kh * 3 + kw;
                    f32x4 w0 = *(const f32x4*)&wl[ci][k][0];
                    f32x4 w1 = *(const f32x4*)&wl[ci][k][4];
                    f32x4 w2v = *(const f32x4*)&wl[ci][k][8];
                    f32x4 w3 = *(const f32x4*)&wl[ci][k][12];
                    a0 += xv * w0; a1 += xv * w1; a2 += xv * w2v; a3 += xv * w3;
                }
            }
        }
    }
    float accs[16];
    #pragma unroll
    for (int i = 0; i < 4; ++i) { accs[i] = a0[i]; accs[4+i] = a1[i]; accs[8+i] = a2[i]; accs[12+i] = a3[i]; }
    #pragma unroll
    for (int o = 0; o < 16; ++o) {
        float v = accs[o];
        if (relu) v = fmaxf(v, 0.f);
        out[((size_t)(b * COUT + o) * TT + t) * 256 + tid] = v;
    }
}

// ---------------------------------------------------------------------------
// instance norm over (T,H,W) per (b,c) + relu, in place. 128 blocks.
// ---------------------------------------------------------------------------
__global__ void inorm_relu_kernel(float* __restrict__ y) {
    __shared__ float s1[256], s2[256];
    float* p = y + (size_t)blockIdx.x * SPAT;
    float sum = 0.f, sq = 0.f;
    for (int i = threadIdx.x; i < SPAT; i += 256) {
        float v = p[i];
        sum += v; sq += v * v;
    }
    s1[threadIdx.x] = sum; s2[threadIdx.x] = sq;
    __syncthreads();
    for (int s = 128; s > 0; s >>= 1) {
        if (threadIdx.x < s) { s1[threadIdx.x] += s1[threadIdx.x + s]; s2[threadIdx.x] += s2[threadIdx.x + s]; }
        __syncthreads();
    }
    float mu = s1[0] / (float)SPAT;
    float var = s2[0] / (float)SPAT - mu * mu;
    float rs = rsqrtf(var + 1e-5f);
    for (int i = threadIdx.x; i < SPAT; i += 256) {
        float v = (p[i] - mu) * rs;
        p[i] = fmaxf(v, 0.f);
    }
}

// ---------------------------------------------------------------------------
// final combine
// ---------------------------------------------------------------------------
__global__ void combine_kernel(const float* __restrict__ hs,
                               const float* __restrict__ out3d,
                               const float* __restrict__ attn_w,
                               const float* __restrict__ attn_b,
                               float* __restrict__ out) {
    int idx = blockIdx.x * 256 + threadIdx.x;
    int hw = idx & 255;
    int t  = (idx >> 8) & 31;
    int b  = idx >> 13;
    const float* hrow = hs + ((size_t)(b * TT + t)) * DOUT;
    float dot = attn_b[0];
    float sv[16], ov[16];
    #pragma unroll
    for (int ch = 0; ch < 16; ++ch) {
        float s  = hrow[ch * 256 + hw];
        float o3 = out3d[(((size_t)(b * COUT + ch) * TT + t)) * 256 + hw];
        sv[ch] = s; ov[ch] = o3;
        dot += attn_w[ch] * s + attn_w[16 + ch] * o3;
    }
    float alpha = 1.f / (1.f + expf(-dot));
    #pragma unroll
    for (int ch = 0; ch < 16; ++ch) {
        out[(((size_t)(b * COUT + ch) * TT + t)) * 256 + hw] =
            alpha * ov[ch] + (1.f - alpha) * sv[ch];
    }
}

// ---------------------------------------------------------------------------
extern "C" void kernel_launch(void* const* d_in, const int* in_sizes, int n_in,
                              void* d_out, int out_size, void* d_ws, size_t ws_size,
                              hipStream_t stream) {
    const float* x      = (const float*)d_in[0];
    const float* c1_w   = (const float*)d_in[1];
    const float* c1_b   = (const float*)d_in[2];
    const float* c2_w   = (const float*)d_in[3];
    const float* c2_b   = (const float*)d_in[4];
    const float* c3_w   = (const float*)d_in[5];
    const float* c3_b   = (const float*)d_in[6];
    const float* pre_w  = (const float*)d_in[7];
    const float* pre_b  = (const float*)d_in[8];
    const float* lstm_W = (const float*)d_in[9];
    const float* lstm_b = (const float*)d_in[10];
    const float* lstm_R = (const float*)d_in[11];
    const float* attn_w = (const float*)d_in[12];
    const float* attn_b = (const float*)d_in[13];
    float* out = (float*)d_out;

    // workspace carve (fp32 first, then bf16/u32; all 16B aligned)
    float* wsf = (float*)d_ws;
    float* y1    = wsf;                // 1048576
    float* y2    = y1 + 1048576;       // 1048576
    float* out3d = y2 + 1048576;       // 1048576
    float* hs    = out3d + 1048576;    // 1048576
    float* Gx    = hs + 1048576;       // 4194304
    ushort_t* xt    = (ushort_t*)(Gx + 4194304);  // 1048576
    ushort_t* xs2b  = xt + 1048576;               // 1048576
    ushort_t* Rp    = xs2b + 1048576;             // 16777216 (packed R, 32 MB)
    unsigned* hsp   = (unsigned*)(Rp + 16777216); // 1048576 u32 (4 MB, per-t h slots)
    int*      flags = (int*)(hsp + 1048576);      // 128 ints

    // zero sync flags (hsp slots are written before they are read)
    hipMemsetAsync(flags, 0, 128 * sizeof(int), stream);

    // pack x -> bf16 sequence layout; pack R -> bf16 MFMA-fragment order
    pack_xt_kernel<<<1024, 256, 0, stream>>>(x, xt);
    pack_R_kernel<<<8192, 256, 0, stream>>>(lstm_R, Rp);

    // convs
    conv3d_kernel<<<256, 256, 0, stream>>>(x, c1_w, c1_b, y1, 0);
    inorm_relu_kernel<<<128, 256, 0, stream>>>(y1);
    conv3d_kernel<<<256, 256, 0, stream>>>(y1, c2_w, c2_b, y2, 1);
    conv3d_kernel<<<256, 256, 0, stream>>>(y2, c3_w, c3_b, out3d, 1);

    // pre-projection -> xs2 (bf16); gate projection -> Gx (fp32)
    mfma_gemm_kernel<true><<<DOUT / 64, 256, 0, stream>>>(xt, pre_w, pre_b, xs2b, DOUT, DIN);
    mfma_gemm_kernel<false><<<4 * DOUT / 64, 256, 0, stream>>>(xs2b, lstm_W, lstm_b, Gx, 4 * DOUT, DOUT);

    // recurrence: one persistent kernel, fence-free flag sync
    lstm_persist_kernel<<<256, 256, 0, stream>>>(Rp, Gx, hsp, hs, flags);

    // combine
    combine_kernel<<<256, 256, 0, stream>>>(hs, out3d, attn_w, attn_b, out);
}

// Round 8
// 676.988 us; speedup vs baseline: 1.5905x; 1.1786x over previous
//
#include <hip/hip_runtime.h>
#include <hip/hip_bf16.h>
#include <cstddef>

// Problem constants
#define BB   8
#define CIN  16
#define COUT 16
#define TT   32
#define HH   16
#define WW   16
#define DIN  4096
#define DOUT 4096
#define NH   4
#define DH   1024
#define SPAT 8192            // T*H*W
#define NSEQ 256             // B*T

typedef __attribute__((ext_vector_type(8))) short  bf16x8;
typedef __attribute__((ext_vector_type(4))) float  f32x4;
typedef __attribute__((ext_vector_type(4))) unsigned short us4;
typedef unsigned short ushort_t;

static __device__ __forceinline__ ushort_t f2bf(float f) {
    union { float f; unsigned u; } v; v.f = f;
    unsigned r = (v.u + 0x7fffu + ((v.u >> 16) & 1u)) >> 16;
    return (ushort_t)r;
}
static __device__ __forceinline__ float bf2f(ushort_t u) {
    union { unsigned u; float f; } v; v.u = ((unsigned)u) << 16;
    return v.f;
}

// ---------------------------------------------------------------------------
// pack x (B,16,32,16,16) fp32 -> xt[n=b*32+t][k=c*256+hw] bf16
// ---------------------------------------------------------------------------
__global__ void pack_xt_kernel(const float* __restrict__ x, ushort_t* __restrict__ xt) {
    int idx = blockIdx.x * 256 + threadIdx.x;          // 0 .. 262143 (4 elems each)
    int n = idx >> 10, k4 = (idx & 1023) * 4;
    int b = n >> 5, t = n & 31, c = k4 >> 8, hw = k4 & 255;
    f32x4 f = *(const f32x4*)&x[(((size_t)(b * CIN + c) * TT + t)) * 256 + hw];
    us4 o;
    #pragma unroll
    for (int i = 0; i < 4; ++i) o[i] = f2bf(f[i]);
    *(us4*)&xt[(size_t)n * DIN + k4] = o;
}

// ---------------------------------------------------------------------------
// pack R (4,4,1024,1024) fp32 -> bf16 in MFMA-fragment order:
// Rp[((head*64+oc)*4+g)*32+ks][lane][e] = R[head][g][oc*16+(lane&15)][ks*32+(lane>>4)*8+e]
// ---------------------------------------------------------------------------
__global__ void pack_R_kernel(const float* __restrict__ R, ushort_t* __restrict__ Rp) {
    int vid = blockIdx.x * 256 + threadIdx.x;   // 0 .. 2097151
    int l  = vid & 63;
    int ks = (vid >> 6) & 31;
    int g  = (vid >> 11) & 3;
    int oc = (vid >> 13) & 63;
    int hd = vid >> 19;
    int arow = l & 15, kI = l >> 4;
    const float* src = R + ((size_t)((hd * 4 + g) * DH + oc * 16 + arow)) * DH
                         + ks * 32 + kI * 8;
    f32x4 f0 = *(const f32x4*)src;
    f32x4 f1 = *(const f32x4*)(src + 4);
    union { ushort_t u[8]; bf16x8 v; } pk;
    #pragma unroll
    for (int j = 0; j < 4; ++j) { pk.u[j] = f2bf(f0[j]); pk.u[4 + j] = f2bf(f1[j]); }
    ((bf16x8*)Rp)[vid] = pk.v;
}

// ---------------------------------------------------------------------------
// MFMA GEMM, single M-tile: C[256][N] = A[256][K](bf16) * B[N][K]^T(fp32) + bias
// BM=256 BN=64 BK=64, 256 threads (4 waves), double-buffered LDS.
// ---------------------------------------------------------------------------
template<bool OUT_BF16>
__global__ __launch_bounds__(256, 2)
void mfma_gemm_kernel(const ushort_t* __restrict__ A, const float* __restrict__ B,
                      const float* __restrict__ bias, void* __restrict__ C,
                      int N, int K) {
    __shared__ ushort_t Al[2][256][64];   // 64 KB
    __shared__ ushort_t Bl[2][64][64];    // 16 KB
    int tid  = threadIdx.x;
    int lane = tid & 63;
    int wv   = tid >> 6;       // 0..3 : wave owns rows [wv*64, wv*64+64)
    int n0 = blockIdx.x * 64;

    f32x4 acc[4][4];
    #pragma unroll
    for (int i = 0; i < 4; ++i)
        #pragma unroll
        for (int j = 0; j < 4; ++j) acc[i][j] = (f32x4){0.f, 0.f, 0.f, 0.f};

    auto stageA = [&](int buf, int k0) {
        #pragma unroll
        for (int q = 0; q < 8; ++q) {
            int row = wv * 64 + q * 8 + (lane >> 3);
            const ushort_t* g = A + (size_t)row * K + k0 + (lane & 7) * 8;
            __builtin_amdgcn_global_load_lds(
                (const __attribute__((address_space(1))) void*)g,
                (__attribute__((address_space(3))) void*)&Al[buf][wv * 64 + q * 8][0],
                16, 0, 0);
        }
    };
    auto stageB = [&](int buf, int k0) {
        int r = tid >> 2;               // 0..63
        int cs = (tid & 3) * 16;        // 0,16,32,48
        const float* g = B + (size_t)(n0 + r) * K + k0 + cs;
        f32x4 f0 = *(const f32x4*)(g);
        f32x4 f1 = *(const f32x4*)(g + 4);
        f32x4 f2 = *(const f32x4*)(g + 8);
        f32x4 f3 = *(const f32x4*)(g + 12);
        union { ushort_t u[16]; bf16x8 v[2]; } pk;
        #pragma unroll
        for (int i = 0; i < 4; ++i) {
            pk.u[i]      = f2bf(f0[i]);
            pk.u[4 + i]  = f2bf(f1[i]);
            pk.u[8 + i]  = f2bf(f2[i]);
            pk.u[12 + i] = f2bf(f3[i]);
        }
        *(bf16x8*)&Bl[buf][r][cs]     = pk.v[0];
        *(bf16x8*)&Bl[buf][r][cs + 8] = pk.v[1];
    };
    auto compute = [&](int buf) {
        #pragma unroll
        for (int ks = 0; ks < 2; ++ks) {
            bf16x8 af[4], bfr[4];
            #pragma unroll
            for (int i = 0; i < 4; ++i)
                af[i] = *(const bf16x8*)&Al[buf][wv * 64 + i * 16 + (lane & 15)][ks * 32 + (lane >> 4) * 8];
            #pragma unroll
            for (int j = 0; j < 4; ++j)
                bfr[j] = *(const bf16x8*)&Bl[buf][j * 16 + (lane & 15)][ks * 32 + (lane >> 4) * 8];
            #pragma unroll
            for (int i = 0; i < 4; ++i)
                #pragma unroll
                for (int j = 0; j < 4; ++j)
                    acc[i][j] = __builtin_amdgcn_mfma_f32_16x16x32_bf16(af[i], bfr[j], acc[i][j], 0, 0, 0);
        }
    };

    stageA(0, 0); stageB(0, 0);
    __syncthreads();
    int nk = K / 64;
    int cur = 0;
    for (int t = 0; t < nk; ++t) {
        if (t + 1 < nk) { stageA(cur ^ 1, (t + 1) * 64); stageB(cur ^ 1, (t + 1) * 64); }
        compute(cur);
        __syncthreads();
        cur ^= 1;
    }

    #pragma unroll
    for (int i = 0; i < 4; ++i) {
        int row = wv * 64 + i * 16 + (lane >> 4) * 4;
        #pragma unroll
        for (int j = 0; j < 4; ++j) {
            int col = n0 + j * 16 + (lane & 15);
            float bv = bias[col];
            #pragma unroll
            for (int r = 0; r < 4; ++r) {
                float v = acc[i][j][r] + bv;
                if constexpr (OUT_BF16) ((ushort_t*)C)[(size_t)(row + r) * N + col] = f2bf(v);
                else                    ((float*)C)[(size_t)(row + r) * N + col] = v;
            }
        }
    }
}

// ---------------------------------------------------------------------------
// Persistent sLSTM, fence-free + contention-free sync:
//  - h transported via hfr[t][head][j][b][k'] u32 = (lo<<16|hi) bf16 pair,
//    ALREADY in MFMA B-fragment order; relaxed agent atomics (LLC-coherent).
//  - per-producer flag slots flags[t][head][oc] (one relaxed store each; no RMW
//    contention); consumers poll lane-parallel (64 contiguous dwords, __all),
//    each wave independently -> no barrier on the detect path.
// grid: 256 blocks = head(4) x ochunk(64 of 16 o's), 256 threads, 1 block/CU.
// wave = K-chunk (8 ks each), all 4 gates per wave; partial-gh reduce in LDS.
// ---------------------------------------------------------------------------
__global__ __launch_bounds__(256, 1)
void lstm_persist_kernel(const ushort_t* __restrict__ Rp,   // packed bf16 (32 MB)
                         const float* __restrict__ Gx,      // [256][16384]
                         unsigned* __restrict__ hfr,        // [32][4][32][8][32] u32
                         float* __restrict__ hs,            // [8][32][4096] f32
                         int* __restrict__ flags) {         // [32][4][64], zeroed
    __shared__ ushort_t Rl[4][32][64 * 8];   // [gate][ks][lane*8] = 128 KB
    __shared__ float gh_p[4][4][16][8];      // [wave][gate][o_l][b] = 8 KB

    int tid  = threadIdx.x;
    int lane = tid & 63;
    int w    = tid >> 6;               // wave = K-chunk (ks in [w*8, w*8+8))
    int head = blockIdx.x >> 6;
    int oc   = blockIdx.x & 63;

    // ---- stage packed R slice (contiguous 128 KB) into LDS, once ----
    const bf16x8* Rsrc = (const bf16x8*)Rp + (size_t)((head * 64 + oc) * 4) * 32 * 64;
    bf16x8* Rdst = (bf16x8*)&Rl[0][0][0];
    for (int i = tid; i < 4 * 32 * 64; i += 256) Rdst[i] = Rsrc[i];

    int arow = lane & 15;          // packed-B column (part,bb); also D column
    int part = arow >> 3;          // 0: hi half of h, 1: lo half
    int bb   = arow & 7;           // batch
    int kseg = lane >> 4;          // 0..3

    // gate-phase identity (tid < 128)
    int gb  = tid >> 4;            // batch
    int gol = tid & 15;            // o_local
    int gd  = head * DH + oc * 16 + gol;
    int o_h = oc * 16 + gol;                      // o within head
    unsigned hslot = ((unsigned)head * 32 + (o_h >> 5)) * 256 + gb * 32 + (o_h & 31);
    float c_r = 0.f, n_r = 0.f, m_r = 0.f;

    __syncthreads();

    for (int t = 0; t < TT; ++t) {
        // prefetch this step's Gx (h-independent) before the flag wait
        float gx0 = 0.f, gx1 = 0.f, gx2 = 0.f, gx3 = 0.f;
        if (tid < 128) {
            size_t gxoff = ((size_t)(gb * TT + t)) * (4 * DOUT) + gd;
            gx0 = Gx[gxoff];
            gx1 = Gx[gxoff + DOUT];
            gx2 = Gx[gxoff + 2 * DOUT];
            gx3 = Gx[gxoff + 3 * DOUT];
        }

        if (t > 0) {
            // lane-parallel poll: 64 producer flags of this head, coalesced
            const int* fl = flags + (((t - 1) * 4 + head) << 6);
            for (;;) {
                int v = __hip_atomic_load(fl + lane, __ATOMIC_RELAXED,
                                          __HIP_MEMORY_SCOPE_AGENT);
                if (__all(v != 0)) break;
                __builtin_amdgcn_s_sleep(1);
            }

            // load h fragments (B-operand layout) as u64 atomic loads
            const unsigned long long* hb = (const unsigned long long*)hfr
                + ((((size_t)(t - 1) * 4 + head) * 32) * 256 + bb * 32 + kseg * 8) / 2;
            bf16x8 hf[8];
            #pragma unroll
            for (int j = 0; j < 8; ++j) {
                const unsigned long long* p = hb + (size_t)(w * 8 + j) * 128;
                union { ushort_t u[8]; bf16x8 v; } fr;
                #pragma unroll
                for (int e2 = 0; e2 < 4; ++e2) {
                    unsigned long long q = __hip_atomic_load(p + e2, __ATOMIC_RELAXED,
                                                             __HIP_MEMORY_SCOPE_AGENT);
                    unsigned q0 = (unsigned)q, q1 = (unsigned)(q >> 32);
                    fr.u[e2 * 2]     = part ? (ushort_t)(q0 >> 16) : (ushort_t)(q0 & 0xffffu);
                    fr.u[e2 * 2 + 1] = part ? (ushort_t)(q1 >> 16) : (ushort_t)(q1 & 0xffffu);
                }
                hf[j] = fr.v;
            }

            f32x4 acc[4];
            #pragma unroll
            for (int g = 0; g < 4; ++g) acc[g] = (f32x4){0.f, 0.f, 0.f, 0.f};
            #pragma unroll
            for (int g = 0; g < 4; ++g)
                #pragma unroll
                for (int j = 0; j < 8; ++j) {
                    bf16x8 a = *(const bf16x8*)&Rl[g][w * 8 + j][lane * 8];
                    acc[g] = __builtin_amdgcn_mfma_f32_16x16x32_bf16(a, hf[j], acc[g], 0, 0, 0);
                }
            // fold hi+lo halves (partner column = col^8 -> lane^8)
            #pragma unroll
            for (int g = 0; g < 4; ++g)
                #pragma unroll
                for (int r = 0; r < 4; ++r)
                    acc[g][r] += __shfl_xor(acc[g][r], 8, 64);
            // D layout: col = lane&15, row = kseg*4 + r
            if (part == 0) {
                int orow0 = kseg * 4;
                #pragma unroll
                for (int g = 0; g < 4; ++g)
                    #pragma unroll
                    for (int r = 0; r < 4; ++r)
                        gh_p[w][g][orow0 + r][bb] = acc[g][r];
            }
        } else {
            for (int i = tid; i < 4 * 4 * 16 * 8; i += 256)
                ((float*)gh_p)[i] = 0.f;
        }
        __syncthreads();

        if (tid < 128) {
            float ip = gx0 +
                gh_p[0][0][gol][gb] + gh_p[1][0][gol][gb] + gh_p[2][0][gol][gb] + gh_p[3][0][gol][gb];
            float fp = gx1 +
                gh_p[0][1][gol][gb] + gh_p[1][1][gol][gb] + gh_p[2][1][gol][gb] + gh_p[3][1][gol][gb];
            float zp = gx2 +
                gh_p[0][2][gol][gb] + gh_p[1][2][gol][gb] + gh_p[2][2][gol][gb] + gh_p[3][2][gol][gb];
            float op = gx3 +
                gh_p[0][3][gol][gb] + gh_p[1][3][gol][gb] + gh_p[2][3][gol][gb] + gh_p[3][3][gol][gb];
            float mn = fmaxf(fp + m_r, ip);
            float iv = expf(ip - mn);
            float fv = expf(fp + m_r - mn);
            c_r = fv * c_r + iv * tanhf(zp);
            n_r = fv * n_r + iv;
            float sig = 1.f / (1.f + expf(-op));
            float hv = sig * c_r / n_r;
            m_r = mn;
            hs[((size_t)(gb * TT + t)) * DOUT + gd] = hv;
            unsigned hi = f2bf(hv);
            unsigned lo = f2bf(hv - bf2f((ushort_t)hi));
            __hip_atomic_store(&hfr[(size_t)t * (4 * 32 * 256) + hslot],
                               hi | (lo << 16),
                               __ATOMIC_RELAXED, __HIP_MEMORY_SCOPE_AGENT);
        }
        __syncthreads();   // drains this block's stores (vmcnt) before signal
        if (tid == 0)
            __hip_atomic_store(&flags[((t * 4 + head) << 6) + oc], 1,
                               __ATOMIC_RELAXED, __HIP_MEMORY_SCOPE_AGENT);
    }
}

// ---------------------------------------------------------------------------
// conv3d 3x3x3 pad=1: one block per (b,t); LDS-staged input slice + weights.
// ---------------------------------------------------------------------------
__global__ __launch_bounds__(256)
void conv3d_kernel(const float* __restrict__ in, const float* __restrict__ w,
                   const float* __restrict__ bias, float* __restrict__ out, int relu) {
    __shared__ float xin[CIN][3][256];      // 48 KB
    __shared__ float wl[CIN][27][16];       // 27 KB, o-fastest
    int b = blockIdx.x >> 5, t = blockIdx.x & 31;
    int tid = threadIdx.x;

    for (int i = tid; i < CIN * 27 * 16; i += 256) {
        int o = i & 15, r = i >> 4;
        int k = r % 27, ci = r / 27;
        wl[ci][k][o] = w[(size_t)(o * CIN + ci) * 27 + k];
    }
    for (int i = tid; i < CIN * 3 * 256; i += 256) {
        int hw = i & 255, r = i >> 8;
        int kt = r % 3, ci = r / 3;
        int tt = t + kt - 1;
        xin[ci][kt][hw] = ((unsigned)tt < TT)
            ? in[((size_t)(b * CIN + ci) * TT + tt) * 256 + hw] : 0.f;
    }
    __syncthreads();

    int h = tid >> 4, wx = tid & 15;
    f32x4 a0 = *(const f32x4*)&bias[0];
    f32x4 a1 = *(const f32x4*)&bias[4];
    f32x4 a2 = *(const f32x4*)&bias[8];
    f32x4 a3 = *(const f32x4*)&bias[12];

    for (int ci = 0; ci < CIN; ++ci) {
        #pragma unroll
        for (int kt = 0; kt < 3; ++kt) {
            #pragma unroll
            for (int kh = 0; kh < 3; ++kh) {
                int h2 = h + kh - 1;
                if ((unsigned)h2 >= HH) continue;
                #pragma unroll
                for (int kw = 0; kw < 3; ++kw) {
                    int w2 = wx + kw - 1;
                    if ((unsigned)w2 >= WW) continue;
                    float xv = xin[ci][kt][h2 * 16 + w2];
                    int k = kt * 9 + kh * 3 + kw;
                    f32x4 w0 = *(const f32x4*)&wl[ci][k][0];
                    f32x4 w1 = *(const f32x4*)&wl[ci][k][4];
                    f32x4 w2v = *(const f32x4*)&wl[ci][k][8];
                    f32x4 w3 = *(const f32x4*)&wl[ci][k][12];
                    a0 += xv * w0; a1 += xv * w1; a2 += xv * w2v; a3 += xv * w3;
                }
            }
        }
    }
    float accs[16];
    #pragma unroll
    for (int i = 0; i < 4; ++i) { accs[i] = a0[i]; accs[4+i] = a1[i]; accs[8+i] = a2[i]; accs[12+i] = a3[i]; }
    #pragma unroll
    for (int o = 0; o < 16; ++o) {
        float v = accs[o];
        if (relu) v = fmaxf(v, 0.f);
        out[((size_t)(b * COUT + o) * TT + t) * 256 + tid] = v;
    }
}

// ---------------------------------------------------------------------------
// instance norm over (T,H,W) per (b,c) + relu, in place. 128 blocks.
// ---------------------------------------------------------------------------
__global__ void inorm_relu_kernel(float* __restrict__ y) {
    __shared__ float s1[256], s2[256];
    float* p = y + (size_t)blockIdx.x * SPAT;
    float sum = 0.f, sq = 0.f;
    for (int i = threadIdx.x; i < SPAT; i += 256) {
        float v = p[i];
        sum += v; sq += v * v;
    }
    s1[threadIdx.x] = sum; s2[threadIdx.x] = sq;
    __syncthreads();
    for (int s = 128; s > 0; s >>= 1) {
        if (threadIdx.x < s) { s1[threadIdx.x] += s1[threadIdx.x + s]; s2[threadIdx.x] += s2[threadIdx.x + s]; }
        __syncthreads();
    }
    float mu = s1[0] / (float)SPAT;
    float var = s2[0] / (float)SPAT - mu * mu;
    float rs = rsqrtf(var + 1e-5f);
    for (int i = threadIdx.x; i < SPAT; i += 256) {
        float v = (p[i] - mu) * rs;
        p[i] = fmaxf(v, 0.f);
    }
}

// ---------------------------------------------------------------------------
// final combine
// ---------------------------------------------------------------------------
__global__ void combine_kernel(const float* __restrict__ hs,
                               const float* __restrict__ out3d,
                               const float* __restrict__ attn_w,
                               const float* __restrict__ attn_b,
                               float* __restrict__ out) {
    int idx = blockIdx.x * 256 + threadIdx.x;
    int hw = idx & 255;
    int t  = (idx >> 8) & 31;
    int b  = idx >> 13;
    const float* hrow = hs + ((size_t)(b * TT + t)) * DOUT;
    float dot = attn_b[0];
    float sv[16], ov[16];
    #pragma unroll
    for (int ch = 0; ch < 16; ++ch) {
        float s  = hrow[ch * 256 + hw];
        float o3 = out3d[(((size_t)(b * COUT + ch) * TT + t)) * 256 + hw];
        sv[ch] = s; ov[ch] = o3;
        dot += attn_w[ch] * s + attn_w[16 + ch] * o3;
    }
    float alpha = 1.f / (1.f + expf(-dot));
    #pragma unroll
    for (int ch = 0; ch < 16; ++ch) {
        out[(((size_t)(b * COUT + ch) * TT + t)) * 256 + hw] =
            alpha * ov[ch] + (1.f - alpha) * sv[ch];
    }
}

// ---------------------------------------------------------------------------
extern "C" void kernel_launch(void* const* d_in, const int* in_sizes, int n_in,
                              void* d_out, int out_size, void* d_ws, size_t ws_size,
                              hipStream_t stream) {
    const float* x      = (const float*)d_in[0];
    const float* c1_w   = (const float*)d_in[1];
    const float* c1_b   = (const float*)d_in[2];
    const float* c2_w   = (const float*)d_in[3];
    const float* c2_b   = (const float*)d_in[4];
    const float* c3_w   = (const float*)d_in[5];
    const float* c3_b   = (const float*)d_in[6];
    const float* pre_w  = (const float*)d_in[7];
    const float* pre_b  = (const float*)d_in[8];
    const float* lstm_W = (const float*)d_in[9];
    const float* lstm_b = (const float*)d_in[10];
    const float* lstm_R = (const float*)d_in[11];
    const float* attn_w = (const float*)d_in[12];
    const float* attn_b = (const float*)d_in[13];
    float* out = (float*)d_out;

    // workspace carve (fp32 first, then bf16/u32; all 16B aligned)
    float* wsf = (float*)d_ws;
    float* y1    = wsf;                // 1048576
    float* y2    = y1 + 1048576;       // 1048576
    float* out3d = y2 + 1048576;       // 1048576
    float* hs    = out3d + 1048576;    // 1048576
    float* Gx    = hs + 1048576;       // 4194304
    ushort_t* xt    = (ushort_t*)(Gx + 4194304);  // 1048576
    ushort_t* xs2b  = xt + 1048576;               // 1048576
    ushort_t* Rp    = xs2b + 1048576;             // 16777216 (packed R, 32 MB)
    unsigned* hfr   = (unsigned*)(Rp + 16777216); // 1048576 u32 (4 MB, fragment h slots)
    int*      flags = (int*)(hfr + 1048576);      // 8192 ints (32 KB)

    // zero sync flags (hfr slots are written before they are read)
    hipMemsetAsync(flags, 0, 8192 * sizeof(int), stream);

    // pack x -> bf16 sequence layout; pack R -> bf16 MFMA-fragment order
    pack_xt_kernel<<<1024, 256, 0, stream>>>(x, xt);
    pack_R_kernel<<<8192, 256, 0, stream>>>(lstm_R, Rp);

    // convs
    conv3d_kernel<<<256, 256, 0, stream>>>(x, c1_w, c1_b, y1, 0);
    inorm_relu_kernel<<<128, 256, 0, stream>>>(y1);
    conv3d_kernel<<<256, 256, 0, stream>>>(y1, c2_w, c2_b, y2, 1);
    conv3d_kernel<<<256, 256, 0, stream>>>(y2, c3_w, c3_b, out3d, 1);

    // pre-projection -> xs2 (bf16); gate projection -> Gx (fp32)
    mfma_gemm_kernel<true><<<DOUT / 64, 256, 0, stream>>>(xt, pre_w, pre_b, xs2b, DOUT, DIN);
    mfma_gemm_kernel<false><<<4 * DOUT / 64, 256, 0, stream>>>(xs2b, lstm_W, lstm_b, Gx, 4 * DOUT, DOUT);

    // recurrence: one persistent kernel, contention-free flag sync
    lstm_persist_kernel<<<256, 256, 0, stream>>>(Rp, Gx, hfr, hs, flags);

    // combine
    combine_kernel<<<256, 256, 0, stream>>>(hs, out3d, attn_w, attn_b, out);
}

// Round 9
// 623.112 us; speedup vs baseline: 1.7280x; 1.0865x over previous
//
#include <hip/hip_runtime.h>
#include <hip/hip_bf16.h>
#include <cstddef>

// Problem constants
#define BB   8
#define CIN  16
#define COUT 16
#define TT   32
#define HH   16
#define WW   16
#define DIN  4096
#define DOUT 4096
#define NH   4
#define DH   1024
#define SPAT 8192            // T*H*W
#define NSEQ 256             // B*T

typedef __attribute__((ext_vector_type(8))) short  bf16x8;
typedef __attribute__((ext_vector_type(4))) float  f32x4;
typedef __attribute__((ext_vector_type(4))) unsigned short us4;
typedef unsigned short ushort_t;

static __device__ __forceinline__ ushort_t f2bf(float f) {
    union { float f; unsigned u; } v; v.f = f;
    unsigned r = (v.u + 0x7fffu + ((v.u >> 16) & 1u)) >> 16;
    return (ushort_t)r;
}
static __device__ __forceinline__ float bf2f(ushort_t u) {
    union { unsigned u; float f; } v; v.u = ((unsigned)u) << 16;
    return v.f;
}

// ---------------------------------------------------------------------------
// pack x (B,16,32,16,16) fp32 -> xt[n=b*32+t][k=c*256+hw] bf16
// ---------------------------------------------------------------------------
__global__ void pack_xt_kernel(const float* __restrict__ x, ushort_t* __restrict__ xt) {
    int idx = blockIdx.x * 256 + threadIdx.x;          // 0 .. 262143 (4 elems each)
    int n = idx >> 10, k4 = (idx & 1023) * 4;
    int b = n >> 5, t = n & 31, c = k4 >> 8, hw = k4 & 255;
    f32x4 f = *(const f32x4*)&x[(((size_t)(b * CIN + c) * TT + t)) * 256 + hw];
    us4 o;
    #pragma unroll
    for (int i = 0; i < 4; ++i) o[i] = f2bf(f[i]);
    *(us4*)&xt[(size_t)n * DIN + k4] = o;
}

// ---------------------------------------------------------------------------
// MFMA GEMM: C[M][N] = A[M][K](bf16) * B[N][K]^T(fp32) + bias
// BM template (64 or 128), BN=64, BK=64; 256 threads (4 waves), dbuf LDS.
// grid (N/64, M/BM).
// ---------------------------------------------------------------------------
template<int BM, bool OUT_BF16>
__global__ __launch_bounds__(256, 2)
void mfma_gemm_kernel(const ushort_t* __restrict__ A, const float* __restrict__ B,
                      const float* __restrict__ bias, void* __restrict__ C,
                      int N, int K) {
    constexpr int FR = BM / 64;           // fragment-rows per wave
    __shared__ ushort_t Al[2][BM][64];
    __shared__ ushort_t Bl[2][64][64];
    int tid  = threadIdx.x;
    int lane = tid & 63;
    int wv   = tid >> 6;       // wave owns rows [wv*BM/4, (wv+1)*BM/4)
    int n0 = blockIdx.x * 64;
    int m0 = blockIdx.y * BM;

    f32x4 acc[FR][4];
    #pragma unroll
    for (int i = 0; i < FR; ++i)
        #pragma unroll
        for (int j = 0; j < 4; ++j) acc[i][j] = (f32x4){0.f, 0.f, 0.f, 0.f};

    auto stageA = [&](int buf, int k0) {
        #pragma unroll
        for (int q = 0; q < BM / 32; ++q) {
            int rbase = wv * (BM / 4) + q * 8;
            const ushort_t* g = A + (size_t)(m0 + rbase + (lane >> 3)) * K + k0 + (lane & 7) * 8;
            __builtin_amdgcn_global_load_lds(
                (const __attribute__((address_space(1))) void*)g,
                (__attribute__((address_space(3))) void*)&Al[buf][rbase][0],
                16, 0, 0);
        }
    };
    auto stageB = [&](int buf, int k0) {
        int r = tid >> 2;               // 0..63
        int cs = (tid & 3) * 16;        // 0,16,32,48
        const float* g = B + (size_t)(n0 + r) * K + k0 + cs;
        f32x4 f0 = *(const f32x4*)(g);
        f32x4 f1 = *(const f32x4*)(g + 4);
        f32x4 f2 = *(const f32x4*)(g + 8);
        f32x4 f3 = *(const f32x4*)(g + 12);
        union { ushort_t u[16]; bf16x8 v[2]; } pk;
        #pragma unroll
        for (int i = 0; i < 4; ++i) {
            pk.u[i]      = f2bf(f0[i]);
            pk.u[4 + i]  = f2bf(f1[i]);
            pk.u[8 + i]  = f2bf(f2[i]);
            pk.u[12 + i] = f2bf(f3[i]);
        }
        *(bf16x8*)&Bl[buf][r][cs]     = pk.v[0];
        *(bf16x8*)&Bl[buf][r][cs + 8] = pk.v[1];
    };
    auto compute = [&](int buf) {
        #pragma unroll
        for (int ks = 0; ks < 2; ++ks) {
            bf16x8 af[FR], bfr[4];
            #pragma unroll
            for (int i = 0; i < FR; ++i)
                af[i] = *(const bf16x8*)&Al[buf][wv * (BM / 4) + i * 16 + (lane & 15)][ks * 32 + (lane >> 4) * 8];
            #pragma unroll
            for (int j = 0; j < 4; ++j)
                bfr[j] = *(const bf16x8*)&Bl[buf][j * 16 + (lane & 15)][ks * 32 + (lane >> 4) * 8];
            #pragma unroll
            for (int i = 0; i < FR; ++i)
                #pragma unroll
                for (int j = 0; j < 4; ++j)
                    acc[i][j] = __builtin_amdgcn_mfma_f32_16x16x32_bf16(af[i], bfr[j], acc[i][j], 0, 0, 0);
        }
    };

    stageA(0, 0); stageB(0, 0);
    __syncthreads();
    int nk = K / 64;
    int cur = 0;
    for (int t = 0; t < nk; ++t) {
        if (t + 1 < nk) { stageA(cur ^ 1, (t + 1) * 64); stageB(cur ^ 1, (t + 1) * 64); }
        compute(cur);
        __syncthreads();
        cur ^= 1;
    }

    #pragma unroll
    for (int i = 0; i < FR; ++i) {
        int row = m0 + wv * (BM / 4) + i * 16 + (lane >> 4) * 4;
        #pragma unroll
        for (int j = 0; j < 4; ++j) {
            int col = n0 + j * 16 + (lane & 15);
            float bv = bias[col];
            #pragma unroll
            for (int r = 0; r < 4; ++r) {
                float v = acc[i][j][r] + bv;
                if constexpr (OUT_BF16) ((ushort_t*)C)[(size_t)(row + r) * N + col] = f2bf(v);
                else                    ((float*)C)[(size_t)(row + r) * N + col] = v;
            }
        }
    }
}

// ---------------------------------------------------------------------------
// Persistent sLSTM, fence-free + fine-grained sync:
//  - R (fp32) staged directly into LDS in MFMA fragment order (coalesced row
//    reads, one-time), no pack kernel, no Rp buffer.
//  - h via hfr[t][head][ks][b][k'] u32 = (lo<<16|hi) bf16 pair, B-fragment
//    order; relaxed agent atomics (LLC-coherent, no cache fences).
//  - flags[t][head][oc][2]: each producing gate-wave stores its own flag right
//    after an inline s_waitcnt vmcnt(0) (no barrier on the signal path).
//    Consumer wave w polls only its 32 flags (oc in [16w,16w+16) x 2 waves).
// grid: 256 blocks = head(4) x ochunk(64 of 16 o's), 256 threads, 1 block/CU.
// ---------------------------------------------------------------------------
__global__ __launch_bounds__(256, 1)
void lstm_persist_kernel(const float* __restrict__ R,       // [4][4][1024][1024] fp32
                         const float* __restrict__ Gx,      // [256][16384]
                         unsigned* __restrict__ hfr,        // [32][4][32][8][32] u32
                         float* __restrict__ hs,            // [8][32][4096] f32
                         int* __restrict__ flags) {         // [32][4][64][2], zeroed
    __shared__ ushort_t Rl[4][32][64 * 8];   // [gate][ks][lane*8] = 128 KB
    __shared__ float gh_p[4][4][16][8];      // [wave][gate][o_l][b] = 8 KB

    int tid  = threadIdx.x;
    int lane = tid & 63;
    int w    = tid >> 6;               // wave = K-chunk (ks in [w*8, w*8+8))
    int head = blockIdx.x >> 6;
    int oc   = blockIdx.x & 63;

    // ---- stage R slice fp32 -> bf16 LDS in fragment order, once ----
    // iteration n handles R row (g = n>>4, r = n&15), this thread column c4=tid
    for (int n = 0; n < 64; ++n) {
        int g = n >> 4, r = n & 15;
        const float* src = R + ((size_t)((head * 4 + g) * DH + oc * 16 + r)) * DH + tid * 4;
        f32x4 f = *(const f32x4*)src;
        int k0 = tid * 4;
        int ks = k0 >> 5;
        int kI = (k0 >> 3) & 3;
        int e8 = k0 & 7;               // 0 or 4
        union { ushort_t u[4]; unsigned long long q; } pk;
        #pragma unroll
        for (int e = 0; e < 4; ++e) pk.u[e] = f2bf(f[e]);
        *(unsigned long long*)&Rl[g][ks][((kI << 4) | r) * 8 + e8] = pk.q;
    }

    int arow = lane & 15;          // packed-B column (part,bb); also D column
    int part = arow >> 3;          // 0: hi half of h, 1: lo half
    int bb   = arow & 7;           // batch
    int kseg = lane >> 4;          // 0..3

    // gate-phase identity (tid < 128)
    int gb  = tid >> 4;            // batch
    int gol = tid & 15;            // o_local
    int gd  = head * DH + oc * 16 + gol;
    int o_h = oc * 16 + gol;                      // o within head
    unsigned hslot = ((unsigned)head * 32 + (o_h >> 5)) * 256 + gb * 32 + (o_h & 31);
    float c_r = 0.f, n_r = 0.f, m_r = 0.f;

    __syncthreads();

    for (int t = 0; t < TT; ++t) {
        // prefetch this step's Gx (h-independent) before the flag wait
        float gx0 = 0.f, gx1 = 0.f, gx2 = 0.f, gx3 = 0.f;
        if (tid < 128) {
            size_t gxoff = ((size_t)(gb * TT + t)) * (4 * DOUT) + gd;
            gx0 = Gx[gxoff];
            gx1 = Gx[gxoff + DOUT];
            gx2 = Gx[gxoff + 2 * DOUT];
            gx3 = Gx[gxoff + 3 * DOUT];
        }

        if (t > 0) {
            // per-wave poll: only the 32 flags of this wave's k-range
            const int* fl = flags + (((t - 1) * 4 + head) << 7) + (w << 5);
            for (;;) {
                int v = __hip_atomic_load(fl + (lane & 31), __ATOMIC_RELAXED,
                                          __HIP_MEMORY_SCOPE_AGENT);
                if (__all(v != 0)) break;
                __builtin_amdgcn_s_sleep(1);
            }

            // load h fragments (B-operand layout) as u64 atomic loads
            const unsigned long long* hb = (const unsigned long long*)hfr
                + ((((size_t)(t - 1) * 4 + head) * 32) * 256 + bb * 32 + kseg * 8) / 2;
            bf16x8 hf[8];
            #pragma unroll
            for (int j = 0; j < 8; ++j) {
                const unsigned long long* p = hb + (size_t)(w * 8 + j) * 128;
                union { ushort_t u[8]; bf16x8 v; } fr;
                #pragma unroll
                for (int e2 = 0; e2 < 4; ++e2) {
                    unsigned long long q = __hip_atomic_load(p + e2, __ATOMIC_RELAXED,
                                                             __HIP_MEMORY_SCOPE_AGENT);
                    unsigned q0 = (unsigned)q, q1 = (unsigned)(q >> 32);
                    fr.u[e2 * 2]     = part ? (ushort_t)(q0 >> 16) : (ushort_t)(q0 & 0xffffu);
                    fr.u[e2 * 2 + 1] = part ? (ushort_t)(q1 >> 16) : (ushort_t)(q1 & 0xffffu);
                }
                hf[j] = fr.v;
            }

            f32x4 acc[4];
            #pragma unroll
            for (int g = 0; g < 4; ++g) acc[g] = (f32x4){0.f, 0.f, 0.f, 0.f};
            #pragma unroll
            for (int g = 0; g < 4; ++g)
                #pragma unroll
                for (int j = 0; j < 8; ++j) {
                    bf16x8 a = *(const bf16x8*)&Rl[g][w * 8 + j][lane * 8];
                    acc[g] = __builtin_amdgcn_mfma_f32_16x16x32_bf16(a, hf[j], acc[g], 0, 0, 0);
                }
            // fold hi+lo halves (partner column = col^8 -> lane^8)
            #pragma unroll
            for (int g = 0; g < 4; ++g)
                #pragma unroll
                for (int r = 0; r < 4; ++r)
                    acc[g][r] += __shfl_xor(acc[g][r], 8, 64);
            // D layout: col = lane&15, row = kseg*4 + r
            if (part == 0) {
                int orow0 = kseg * 4;
                #pragma unroll
                for (int g = 0; g < 4; ++g)
                    #pragma unroll
                    for (int r = 0; r < 4; ++r)
                        gh_p[w][g][orow0 + r][bb] = acc[g][r];
            }
        } else {
            for (int i = tid; i < 4 * 4 * 16 * 8; i += 256)
                ((float*)gh_p)[i] = 0.f;
        }
        __syncthreads();

        if (tid < 128) {
            float ip = gx0 +
                gh_p[0][0][gol][gb] + gh_p[1][0][gol][gb] + gh_p[2][0][gol][gb] + gh_p[3][0][gol][gb];
            float fp = gx1 +
                gh_p[0][1][gol][gb] + gh_p[1][1][gol][gb] + gh_p[2][1][gol][gb] + gh_p[3][1][gol][gb];
            float zp = gx2 +
                gh_p[0][2][gol][gb] + gh_p[1][2][gol][gb] + gh_p[2][2][gol][gb] + gh_p[3][2][gol][gb];
            float op = gx3 +
                gh_p[0][3][gol][gb] + gh_p[1][3][gol][gb] + gh_p[2][3][gol][gb] + gh_p[3][3][gol][gb];
            float mn = fmaxf(fp + m_r, ip);
            float iv = expf(ip - mn);
            float fv = expf(fp + m_r - mn);
            c_r = fv * c_r + iv * tanhf(zp);
            n_r = fv * n_r + iv;
            float sig = 1.f / (1.f + expf(-op));
            float hv = sig * c_r / n_r;
            m_r = mn;
            hs[((size_t)(gb * TT + t)) * DOUT + gd] = hv;
            unsigned hi = f2bf(hv);
            unsigned lo = f2bf(hv - bf2f((ushort_t)hi));
            __hip_atomic_store(&hfr[(size_t)t * (4 * 32 * 256) + hslot],
                               hi | (lo << 16),
                               __ATOMIC_RELAXED, __HIP_MEMORY_SCOPE_AGENT);
            // signal as soon as THIS wave's stores are globally ordered
            asm volatile("s_waitcnt vmcnt(0)" ::: "memory");
            if ((tid & 63) == 0)
                __hip_atomic_store(&flags[((t * 4 + head) << 7) + oc * 2 + (tid >> 6)], 1,
                                   __ATOMIC_RELAXED, __HIP_MEMORY_SCOPE_AGENT);
        }
        __syncthreads();   // protects gh_p reuse across steps
    }
}

// ---------------------------------------------------------------------------
// conv3d 3x3x3 pad=1: one block per (b,t); LDS-staged input slice + weights.
// ---------------------------------------------------------------------------
__global__ __launch_bounds__(256)
void conv3d_kernel(const float* __restrict__ in, const float* __restrict__ w,
                   const float* __restrict__ bias, float* __restrict__ out, int relu) {
    __shared__ float xin[CIN][3][256];      // 48 KB
    __shared__ float wl[CIN][27][16];       // 27 KB, o-fastest
    int b = blockIdx.x >> 5, t = blockIdx.x & 31;
    int tid = threadIdx.x;

    for (int i = tid; i < CIN * 27 * 16; i += 256) {
        int o = i & 15, r = i >> 4;
        int k = r % 27, ci = r / 27;
        wl[ci][k][o] = w[(size_t)(o * CIN + ci) * 27 + k];
    }
    for (int i = tid; i < CIN * 3 * 256; i += 256) {
        int hw = i & 255, r = i >> 8;
        int kt = r % 3, ci = r / 3;
        int tt = t + kt - 1;
        xin[ci][kt][hw] = ((unsigned)tt < TT)
            ? in[((size_t)(b * CIN + ci) * TT + tt) * 256 + hw] : 0.f;
    }
    __syncthreads();

    int h = tid >> 4, wx = tid & 15;
    f32x4 a0 = *(const f32x4*)&bias[0];
    f32x4 a1 = *(const f32x4*)&bias[4];
    f32x4 a2 = *(const f32x4*)&bias[8];
    f32x4 a3 = *(const f32x4*)&bias[12];

    for (int ci = 0; ci < CIN; ++ci) {
        #pragma unroll
        for (int kt = 0; kt < 3; ++kt) {
            #pragma unroll
            for (int kh = 0; kh < 3; ++kh) {
                int h2 = h + kh - 1;
                if ((unsigned)h2 >= HH) continue;
                #pragma unroll
                for (int kw = 0; kw < 3; ++kw) {
                    int w2 = wx + kw - 1;
                    if ((unsigned)w2 >= WW) continue;
                    float xv = xin[ci][kt][h2 * 16 + w2];
                    int k = kt * 9 + kh * 3 + kw;
                    f32x4 w0 = *(const f32x4*)&wl[ci][k][0];
                    f32x4 w1 = *(const f32x4*)&wl[ci][k][4];
                    f32x4 w2v = *(const f32x4*)&wl[ci][k][8];
                    f32x4 w3 = *(const f32x4*)&wl[ci][k][12];
                    a0 += xv * w0; a1 += xv * w1; a2 += xv * w2v; a3 += xv * w3;
                }
            }
        }
    }
    float accs[16];
    #pragma unroll
    for (int i = 0; i < 4; ++i) { accs[i] = a0[i]; accs[4+i] = a1[i]; accs[8+i] = a2[i]; accs[12+i] = a3[i]; }
    #pragma unroll
    for (int o = 0; o < 16; ++o) {
        float v = accs[o];
        if (relu) v = fmaxf(v, 0.f);
        out[((size_t)(b * COUT + o) * TT + t) * 256 + tid] = v;
    }
}

// ---------------------------------------------------------------------------
// instance norm over (T,H,W) per (b,c) + relu, in place. 128 blocks.
// ---------------------------------------------------------------------------
__global__ void inorm_relu_kernel(float* __restrict__ y) {
    __shared__ float s1[256], s2[256];
    float* p = y + (size_t)blockIdx.x * SPAT;
    float sum = 0.f, sq = 0.f;
    for (int i = threadIdx.x; i < SPAT; i += 256) {
        float v = p[i];
        sum += v; sq += v * v;
    }
    s1[threadIdx.x] = sum; s2[threadIdx.x] = sq;
    __syncthreads();
    for (int s = 128; s > 0; s >>= 1) {
        if (threadIdx.x < s) { s1[threadIdx.x] += s1[threadIdx.x + s]; s2[threadIdx.x] += s2[threadIdx.x + s]; }
        __syncthreads();
    }
    float mu = s1[0] / (float)SPAT;
    float var = s2[0] / (float)SPAT - mu * mu;
    float rs = rsqrtf(var + 1e-5f);
    for (int i = threadIdx.x; i < SPAT; i += 256) {
        float v = (p[i] - mu) * rs;
        p[i] = fmaxf(v, 0.f);
    }
}

// ---------------------------------------------------------------------------
// final combine
// ---------------------------------------------------------------------------
__global__ void combine_kernel(const float* __restrict__ hs,
                               const float* __restrict__ out3d,
                               const float* __restrict__ attn_w,
                               const float* __restrict__ attn_b,
                               float* __restrict__ out) {
    int idx = blockIdx.x * 256 + threadIdx.x;
    int hw = idx & 255;
    int t  = (idx >> 8) & 31;
    int b  = idx >> 13;
    const float* hrow = hs + ((size_t)(b * TT + t)) * DOUT;
    float dot = attn_b[0];
    float sv[16], ov[16];
    #pragma unroll
    for (int ch = 0; ch < 16; ++ch) {
        float s  = hrow[ch * 256 + hw];
        float o3 = out3d[(((size_t)(b * COUT + ch) * TT + t)) * 256 + hw];
        sv[ch] = s; ov[ch] = o3;
        dot += attn_w[ch] * s + attn_w[16 + ch] * o3;
    }
    float alpha = 1.f / (1.f + expf(-dot));
    #pragma unroll
    for (int ch = 0; ch < 16; ++ch) {
        out[(((size_t)(b * COUT + ch) * TT + t)) * 256 + hw] =
            alpha * ov[ch] + (1.f - alpha) * sv[ch];
    }
}

// ---------------------------------------------------------------------------
extern "C" void kernel_launch(void* const* d_in, const int* in_sizes, int n_in,
                              void* d_out, int out_size, void* d_ws, size_t ws_size,
                              hipStream_t stream) {
    const float* x      = (const float*)d_in[0];
    const float* c1_w   = (const float*)d_in[1];
    const float* c1_b   = (const float*)d_in[2];
    const float* c2_w   = (const float*)d_in[3];
    const float* c2_b   = (const float*)d_in[4];
    const float* c3_w   = (const float*)d_in[5];
    const float* c3_b   = (const float*)d_in[6];
    const float* pre_w  = (const float*)d_in[7];
    const float* pre_b  = (const float*)d_in[8];
    const float* lstm_W = (const float*)d_in[9];
    const float* lstm_b = (const float*)d_in[10];
    const float* lstm_R = (const float*)d_in[11];
    const float* attn_w = (const float*)d_in[12];
    const float* attn_b = (const float*)d_in[13];
    float* out = (float*)d_out;

    // workspace carve (fp32 first, then bf16/u32; all 16B aligned)
    float* wsf = (float*)d_ws;
    float* y1    = wsf;                // 1048576
    float* y2    = y1 + 1048576;       // 1048576
    float* out3d = y2 + 1048576;       // 1048576
    float* hs    = out3d + 1048576;    // 1048576
    float* Gx    = hs + 1048576;       // 4194304
    ushort_t* xt    = (ushort_t*)(Gx + 4194304);  // 1048576
    ushort_t* xs2b  = xt + 1048576;               // 1048576
    unsigned* hfr   = (unsigned*)(xs2b + 1048576);// 1048576 u32 (4 MB, fragment h slots)
    int*      flags = (int*)(hfr + 1048576);      // 16384 ints (64 KB)

    // zero sync flags (hfr slots are written before they are read)
    hipMemsetAsync(flags, 0, 16384 * sizeof(int), stream);

    // pack x -> bf16 sequence layout
    pack_xt_kernel<<<1024, 256, 0, stream>>>(x, xt);

    // convs
    conv3d_kernel<<<256, 256, 0, stream>>>(x, c1_w, c1_b, y1, 0);
    inorm_relu_kernel<<<128, 256, 0, stream>>>(y1);
    conv3d_kernel<<<256, 256, 0, stream>>>(y1, c2_w, c2_b, y2, 1);
    conv3d_kernel<<<256, 256, 0, stream>>>(y2, c3_w, c3_b, out3d, 1);

    // pre-projection -> xs2 (bf16): 256 blocks; gate projection -> Gx: 512 blocks
    mfma_gemm_kernel<64, true><<<dim3(DOUT / 64, NSEQ / 64), 256, 0, stream>>>(
        xt, pre_w, pre_b, xs2b, DOUT, DIN);
    mfma_gemm_kernel<128, false><<<dim3(4 * DOUT / 64, NSEQ / 128), 256, 0, stream>>>(
        xs2b, lstm_W, lstm_b, Gx, 4 * DOUT, DOUT);

    // recurrence: one persistent kernel, per-wave fine-grained flag sync
    lstm_persist_kernel<<<256, 256, 0, stream>>>(lstm_R, Gx, hfr, hs, flags);

    // combine
    combine_kernel<<<256, 256, 0, stream>>>(hs, out3d, attn_w, attn_b, out);
}